// Round 1
// baseline (1965.140 us; speedup 1.0000x reference)
//
#include <hip/hip_runtime.h>
#include <cstdint>
#include <cstddef>

typedef __attribute__((ext_vector_type(8))) short short8;
typedef __attribute__((ext_vector_type(4))) float f32x4;
typedef __attribute__((ext_vector_type(2))) float f32x2;
typedef __attribute__((ext_vector_type(2))) unsigned int u32x2;

#define SEQ 2048
#define NB  64
#define HID 256
#define M_TOTAL (SEQ*NB)   // 131072

__device__ __forceinline__ unsigned short f2bf(float x){
  unsigned u = __float_as_uint(x);
  u += 0x7fffu + ((u>>16)&1u);
  return (unsigned short)(u>>16);
}

// quad_perm DPP rotate: returns value of lane (quadpos rotated) within each quad
template<int CTRL>
__device__ __forceinline__ float dpp_rot(float x){
  return __int_as_float(__builtin_amdgcn_update_dpp(
      0, __float_as_int(x), CTRL, 0xF, 0xF, true));
}

// ---------- convert x fp32 -> bf16 (4 elems/thread) ----------
__global__ void k_convert_x(const float* __restrict__ x, unsigned short* __restrict__ xb){
  size_t i = (size_t)blockIdx.x*256 + threadIdx.x;   // 0 .. 8388607
  f32x4 v = ((const f32x4*)x)[i];
  unsigned a0=f2bf(v[0]), a1=f2bf(v[1]), a2=f2bf(v[2]), a3=f2bf(v[3]);
  u32x2 o; o[0] = a0 | (a1<<16); o[1] = a2 | (a3<<16);
  ((u32x2*)xb)[i] = o;
}

// ---------- build transposed bf16 weights: BT[n][k] = W[k][n] ----------
__global__ void k_convert_w(const float* __restrict__ i2h, const float* __restrict__ h2o,
                            unsigned short* __restrict__ BT1, unsigned short* __restrict__ BT3){
  int k = blockIdx.x; int n = threadIdx.x;
  BT1[n*256+k] = f2bf(i2h[k*256+n]);   // W_xh = i2h_weight rows [0,256)
  BT3[n*256+k] = f2bf(h2o[k*256+n]);
}

// ---------- bf16 MFMA GEMM: C[M x 256] = A[M x 256] * B + bias ----------
__global__ __launch_bounds__(256) void k_gemm(
    const unsigned short* __restrict__ A, const unsigned short* __restrict__ BT,
    const float* __restrict__ bias, float* __restrict__ C)
{
  __shared__ __align__(16) unsigned short As[128*64];
  __shared__ __align__(16) unsigned short Bs[128*64];
  int tid = threadIdx.x;
  int bm = blockIdx.x, bn = blockIdx.y;
  int l = tid & 63, wv = tid >> 6;
  int wm = wv >> 1, wn = wv & 1;
  int lr = l & 15, lq = l >> 4;

  f32x4 acc[4][4];
  #pragma unroll
  for (int i=0;i<4;i++)
    #pragma unroll
    for (int j=0;j<4;j++) acc[i][j] = (f32x4)0.f;

  for (int kb=0; kb<4; ++kb){
    int k0 = kb*64;
    #pragma unroll
    for (int it=0; it<4; ++it){
      int f = it*256 + tid;
      int m = f >> 3;
      int kk = (f & 7) * 8;
      short8 va = *(const short8*)(A  + (size_t)(bm*128+m)*256 + k0 + kk);
      short8 vb = *(const short8*)(BT + (size_t)(bn*128+m)*256 + k0 + kk);
      *(short8*)(As + m*64 + kk) = va;
      *(short8*)(Bs + m*64 + kk) = vb;
    }
    __syncthreads();
    #pragma unroll
    for (int kt=0; kt<2; ++kt){
      short8 af[4], bfr[4];
      #pragma unroll
      for (int mt=0;mt<4;mt++){
        int row = wm*64 + mt*16 + lr;
        af[mt] = *(const short8*)(As + row*64 + kt*32 + lq*8);
      }
      #pragma unroll
      for (int nt=0;nt<4;nt++){
        int row = wn*64 + nt*16 + lr;
        bfr[nt] = *(const short8*)(Bs + row*64 + kt*32 + lq*8);
      }
      #pragma unroll
      for (int mt=0;mt<4;mt++)
        #pragma unroll
        for (int nt=0;nt<4;nt++)
          acc[mt][nt] = __builtin_amdgcn_mfma_f32_16x16x32_bf16(af[mt], bfr[nt], acc[mt][nt], 0, 0, 0);
    }
    __syncthreads();
  }
  #pragma unroll
  for (int nt=0;nt<4;nt++){
    int gn = bn*128 + wn*64 + nt*16 + lr;
    float bv = bias[gn];
    #pragma unroll
    for (int mt=0;mt<4;mt++){
      int gm = bm*128 + wm*64 + mt*16 + lq*4;
      #pragma unroll
      for (int r=0;r<4;r++)
        C[(size_t)(gm+r)*256 + gn] = acc[mt][nt][r] + bv;
    }
  }
}

// ---------- sequential scan: h_t = tanh(pre_t + h_{t-1} @ W_hh) ----------
// One block per batch, 1024 threads (16 waves).
// k-split 256 = 4 (across waves, ks=wv&3) x 4 (within quad, kc=l&3) x 16 (in regs).
// Thread (ks, kc, jgw=wv>>2, jgl=l>>2) holds W_hh[ks*64+kc*16+m][j0..j0+3],
// m=0..15, in 16 f32x4 VGPRs, PINNED via empty asm so the compiler cannot
// demote them (previous version: VGPR_Count=44 < 64 needed -> W was re-fetched
// from L2 every step; that re-fetch + 2 full-drain __syncthreads were the
// measured 1600 cy/step).
// Reduction: quad all-reduce via 2 DPP-rotate adds (no LDS, no barrier), then
// 4-entry LDS reduce (red = 4x256 floats). Barriers are raw s_barrier with
// lgkmcnt-only drain so H stores + 2-deep pre prefetch stay in flight.
__global__ __launch_bounds__(1024, 4) void k_scan(
    const float* __restrict__ i2h,     // (512,256); W_hh = rows [256,512)
    const float* __restrict__ h0,      // (64,256)
    const float* __restrict__ pre,     // (SEQ*NB,256) fp32 (lives in d_out)
    unsigned short* __restrict__ H)    // (SEQ*NB,256) bf16 out
{
  __shared__ __align__(16) float hbuf[256];
  __shared__ __align__(16) float red[4*256];
  const int b   = blockIdx.x;
  const int tid = threadIdx.x;
  const int l   = tid & 63;
  const int wv  = tid >> 6;          // 0..15
  const int ks  = wv & 3;            // wave-level k chunk (64 k)
  const int kc  = l & 3;             // quad-level k chunk (16 k)
  const int j0  = (wv >> 2)*64 + (l >> 2)*4;   // output col group

  // W_hh fragment: wr[m] = W_hh[ks*64 + kc*16 + m][j0..j0+3]
  f32x4 wr[16];
  {
    const float* Wb = i2h + (size_t)256*256 + ((size_t)(ks*64 + kc*16))*256 + j0;
    #pragma unroll
    for (int m=0;m<16;m++) wr[m] = *(const f32x4*)(Wb + (size_t)m*256);
  }
  #pragma unroll
  for (int m=0;m<16;m++) asm volatile("" : "+v"(wr[m]));   // pin in VGPRs

  if (tid < 256) hbuf[tid] = h0[b*256 + tid];

  // pre prefetch, 2 steps deep (finish lanes = waves 0-3, thread j = tid)
  float pv = 0.f, p1 = 0.f;
  const float* prep = pre + (size_t)b*256 + tid;
  unsigned short* Hp = H + (size_t)b*256 + tid;
  if (tid < 256){
    pv = prep[0];                      // t=0
    p1 = prep[(size_t)NB*256];         // t=1
    prep += (size_t)2*NB*256;
  }
  __syncthreads();

  // wave-uniform ks + 4 distinct kc addrs -> 16-lane broadcast, <=2-way bank
  const f32x4* hv = (const f32x4*)hbuf + (ks*16 + kc*4);
  float* redw = red + ks*256 + j0;

  for (int t=0; t<SEQ; ++t){
    // ---- phase A: partial matvec (all 16 waves) ----
    f32x4 hA = hv[0], hB = hv[1], hC = hv[2], hD = hv[3];
    f32x4 a0, a1;
    a0  = hA[0]*wr[0];   a1  = hA[1]*wr[1];
    a0 += hA[2]*wr[2];   a1 += hA[3]*wr[3];
    a0 += hB[0]*wr[4];   a1 += hB[1]*wr[5];
    a0 += hB[2]*wr[6];   a1 += hB[3]*wr[7];
    a0 += hC[0]*wr[8];   a1 += hC[1]*wr[9];
    a0 += hC[2]*wr[10];  a1 += hC[3]*wr[11];
    a0 += hD[0]*wr[12];  a1 += hD[1]*wr[13];
    a0 += hD[2]*wr[14];  a1 += hD[3]*wr[15];
    f32x4 acc = a0 + a1;

    // ---- quad all-reduce over kc via DPP rotations (VALU only) ----
    #pragma unroll
    for (int c=0;c<4;c++){
      float v = acc[c];
      v += dpp_rot<0x39>(v);   // + lane(q+1 mod 4): perm {1,2,3,0}
      v += dpp_rot<0x4E>(v);   // + rotated by 2:    perm {2,3,0,1}
      acc[c] = v;
    }
    if (kc == 0) *(f32x4*)redw = acc;   // one writer per quad

    asm volatile("s_waitcnt lgkmcnt(0)" ::: "memory");
    __builtin_amdgcn_s_barrier();
    asm volatile("" ::: "memory");

    // ---- phase B: finish (waves 0-3; thread handles output j = tid) ----
    if (tid < 256){
      float p2 = 0.f;
      if (t + 2 < SEQ) p2 = prep[0];
      prep += (size_t)NB*256;
      float s = pv + red[tid] + red[256+tid] + red[512+tid] + red[768+tid];
      float e = __expf(2.f*s);          // tanh(s) = 1 - 2/(e^(2s)+1)
      float h = 1.f - 2.f*__builtin_amdgcn_rcpf(e + 1.f);
      hbuf[tid] = h;
      *Hp = f2bf(h);                    // store stays in flight (no vmcnt drain)
      Hp += (size_t)NB*256;
      pv = p1; p1 = p2;
    }

    asm volatile("s_waitcnt lgkmcnt(0)" ::: "memory");
    __builtin_amdgcn_s_barrier();
    asm volatile("" ::: "memory");
  }
}

extern "C" void kernel_launch(void* const* d_in, const int* in_sizes, int n_in,
                              void* d_out, int out_size, void* d_ws, size_t ws_size,
                              hipStream_t stream) {
  const float* x     = (const float*)d_in[0];
  const float* h0    = (const float*)d_in[1];
  const float* i2h   = (const float*)d_in[2];
  const float* i2h_b = (const float*)d_in[3];
  const float* h2o   = (const float*)d_in[4];
  const float* h2o_b = (const float*)d_in[5];
  float* out = (float*)d_out;

  // ws layout: [0,64MB) x_bf16, later aliased by H_bf16 (x_bf16 dead after gemm1)
  //            [64MB, +256KB) BT1, BT3
  unsigned short* xb  = (unsigned short*)d_ws;
  unsigned short* BT1 = (unsigned short*)((char*)d_ws + (size_t)M_TOTAL*HID*2);
  unsigned short* BT3 = BT1 + 256*256;

  k_convert_x<<<M_TOTAL*HID/(256*4), 256, 0, stream>>>(x, xb);
  k_convert_w<<<256, 256, 0, stream>>>(i2h, h2o, BT1, BT3);

  dim3 g1(M_TOTAL/128, 2);
  // pre = x @ W_xh + i2h_bias  -> stored in d_out (fp32), consumed by scan
  k_gemm<<<g1, 256, 0, stream>>>(xb, BT1, i2h_b, out);
  // sequential recurrence; writes H (bf16) over the xb region
  k_scan<<<NB, 1024, 0, stream>>>(i2h, h0, out, xb);
  // y = H @ W_ho + h2o_bias -> d_out (overwrites pre)
  k_gemm<<<g1, 256, 0, stream>>>(xb, BT3, h2o_b, out);
}

// Round 2
// 1894.653 us; speedup vs baseline: 1.0372x; 1.0372x over previous
//
#include <hip/hip_runtime.h>
#include <cstdint>
#include <cstddef>

typedef __attribute__((ext_vector_type(8))) short short8;
typedef __attribute__((ext_vector_type(4))) float f32x4;
typedef __attribute__((ext_vector_type(2))) float f32x2;
typedef __attribute__((ext_vector_type(2))) unsigned int u32x2;

#define SEQ 2048
#define NB  64
#define HID 256
#define M_TOTAL (SEQ*NB)   // 131072

__device__ __forceinline__ unsigned short f2bf(float x){
  unsigned u = __float_as_uint(x);
  u += 0x7fffu + ((u>>16)&1u);
  return (unsigned short)(u>>16);
}

// quad_perm DPP rotate: returns value of lane (quadpos rotated) within each quad
template<int CTRL>
__device__ __forceinline__ float dpp_rot(float x){
  return __int_as_float(__builtin_amdgcn_update_dpp(
      0, __float_as_int(x), CTRL, 0xF, 0xF, true));
}

// ---------- convert x fp32 -> bf16 (4 elems/thread) ----------
__global__ void k_convert_x(const float* __restrict__ x, unsigned short* __restrict__ xb){
  size_t i = (size_t)blockIdx.x*256 + threadIdx.x;   // 0 .. 8388607
  f32x4 v = ((const f32x4*)x)[i];
  unsigned a0=f2bf(v[0]), a1=f2bf(v[1]), a2=f2bf(v[2]), a3=f2bf(v[3]);
  u32x2 o; o[0] = a0 | (a1<<16); o[1] = a2 | (a3<<16);
  ((u32x2*)xb)[i] = o;
}

// ---------- build transposed bf16 weights: BT[n][k] = W[k][n] ----------
__global__ void k_convert_w(const float* __restrict__ i2h, const float* __restrict__ h2o,
                            unsigned short* __restrict__ BT1, unsigned short* __restrict__ BT3){
  int k = blockIdx.x; int n = threadIdx.x;
  BT1[n*256+k] = f2bf(i2h[k*256+n]);   // W_xh = i2h_weight rows [0,256)
  BT3[n*256+k] = f2bf(h2o[k*256+n]);
}

// ---------- bf16 MFMA GEMM: C[M x 256] = A[M x 256] * B + bias ----------
__global__ __launch_bounds__(256) void k_gemm(
    const unsigned short* __restrict__ A, const unsigned short* __restrict__ BT,
    const float* __restrict__ bias, float* __restrict__ C)
{
  __shared__ __align__(16) unsigned short As[128*64];
  __shared__ __align__(16) unsigned short Bs[128*64];
  int tid = threadIdx.x;
  int bm = blockIdx.x, bn = blockIdx.y;
  int l = tid & 63, wv = tid >> 6;
  int wm = wv >> 1, wn = wv & 1;
  int lr = l & 15, lq = l >> 4;

  f32x4 acc[4][4];
  #pragma unroll
  for (int i=0;i<4;i++)
    #pragma unroll
    for (int j=0;j<4;j++) acc[i][j] = (f32x4)0.f;

  for (int kb=0; kb<4; ++kb){
    int k0 = kb*64;
    #pragma unroll
    for (int it=0; it<4; ++it){
      int f = it*256 + tid;
      int m = f >> 3;
      int kk = (f & 7) * 8;
      short8 va = *(const short8*)(A  + (size_t)(bm*128+m)*256 + k0 + kk);
      short8 vb = *(const short8*)(BT + (size_t)(bn*128+m)*256 + k0 + kk);
      *(short8*)(As + m*64 + kk) = va;
      *(short8*)(Bs + m*64 + kk) = vb;
    }
    __syncthreads();
    #pragma unroll
    for (int kt=0; kt<2; ++kt){
      short8 af[4], bfr[4];
      #pragma unroll
      for (int mt=0;mt<4;mt++){
        int row = wm*64 + mt*16 + lr;
        af[mt] = *(const short8*)(As + row*64 + kt*32 + lq*8);
      }
      #pragma unroll
      for (int nt=0;nt<4;nt++){
        int row = wn*64 + nt*16 + lr;
        bfr[nt] = *(const short8*)(Bs + row*64 + kt*32 + lq*8);
      }
      #pragma unroll
      for (int mt=0;mt<4;mt++)
        #pragma unroll
        for (int nt=0;nt<4;nt++)
          acc[mt][nt] = __builtin_amdgcn_mfma_f32_16x16x32_bf16(af[mt], bfr[nt], acc[mt][nt], 0, 0, 0);
    }
    __syncthreads();
  }
  #pragma unroll
  for (int nt=0;nt<4;nt++){
    int gn = bn*128 + wn*64 + nt*16 + lr;
    float bv = bias[gn];
    #pragma unroll
    for (int mt=0;mt<4;mt++){
      int gm = bm*128 + wm*64 + mt*16 + lq*4;
      #pragma unroll
      for (int r=0;r<4;r++)
        C[(size_t)(gm+r)*256 + gn] = acc[mt][nt][r] + bv;
    }
  }
}

// ---------- sequential scan: h_t = tanh(pre_t + h_{t-1} @ W_hh) ----------
// One block per batch, 1024 threads (16 waves).
// k-split 256 = 4 (across waves, ks=wv&3) x 4 (within quad, kc=l&3) x 16 (in regs).
// Thread (ks, kc, jgw=wv>>2, jgl=l>>2) holds W_hh[ks*64+kc*16+m][j0..j0+3],
// m=0..15, in 16 f32x4 VGPRs.
//
// CRITICAL: amdgpu_waves_per_eu(4,4). With plain __launch_bounds__(1024,4)
// (min only), the backend's occupancy heuristic targeted 8 waves/EU and
// capped VGPRs at 64 (measured: 44 @ r0, 48 @ r1) -> W_hh was re-fetched
// (r0: from L2 global) or spilled to scratch and reloaded (r1) EVERY step,
// ~64 KB/CU/step injected into the serial chain. Pinning min=max=4 waves/EU
// raises the allocator budget AND target to 128 VGPRs so the 64 W regs stay
// resident. The empty-asm pin below prevents the remat-from-global choice.
//
// Reduction: quad all-reduce via 2 DPP-rotate adds (no LDS, no barrier), then
// 4-entry LDS reduce (red = 4x256 floats). Barriers are raw s_barrier with
// lgkmcnt-only drain so H stores + 2-deep pre prefetch stay in flight.
__global__ __launch_bounds__(1024)
__attribute__((amdgpu_waves_per_eu(4, 4)))
void k_scan(
    const float* __restrict__ i2h,     // (512,256); W_hh = rows [256,512)
    const float* __restrict__ h0,      // (64,256)
    const float* __restrict__ pre,     // (SEQ*NB,256) fp32 (lives in d_out)
    unsigned short* __restrict__ H)    // (SEQ*NB,256) bf16 out
{
  __shared__ __align__(16) float hbuf[256];
  __shared__ __align__(16) float red[4*256];
  const int b   = blockIdx.x;
  const int tid = threadIdx.x;
  const int l   = tid & 63;
  const int wv  = tid >> 6;          // 0..15
  const int ks  = wv & 3;            // wave-level k chunk (64 k)
  const int kc  = l & 3;             // quad-level k chunk (16 k)
  const int j0  = (wv >> 2)*64 + (l >> 2)*4;   // output col group

  // W_hh fragment: wr[m] = W_hh[ks*64 + kc*16 + m][j0..j0+3]
  f32x4 wr[16];
  {
    const float* Wb = i2h + (size_t)256*256 + ((size_t)(ks*64 + kc*16))*256 + j0;
    #pragma unroll
    for (int m=0;m<16;m++) wr[m] = *(const f32x4*)(Wb + (size_t)m*256);
  }
  #pragma unroll
  for (int m=0;m<16;m++) asm volatile("" : "+v"(wr[m]));   // pin in VGPRs

  if (tid < 256) hbuf[tid] = h0[b*256 + tid];

  // pre prefetch, 2 steps deep (finish lanes = waves 0-3, thread j = tid)
  float pv = 0.f, p1 = 0.f;
  const float* prep = pre + (size_t)b*256 + tid;
  unsigned short* Hp = H + (size_t)b*256 + tid;
  if (tid < 256){
    pv = prep[0];                      // t=0
    p1 = prep[(size_t)NB*256];         // t=1
    prep += (size_t)2*NB*256;
  }
  __syncthreads();

  // wave-uniform ks + 4 distinct kc addrs -> 16-lane broadcast, <=2-way bank
  const f32x4* hv = (const f32x4*)hbuf + (ks*16 + kc*4);
  float* redw = red + ks*256 + j0;

  for (int t=0; t<SEQ; ++t){
    // ---- phase A: partial matvec (all 16 waves) ----
    f32x4 hA = hv[0], hB = hv[1], hC = hv[2], hD = hv[3];
    f32x4 a0, a1;
    a0  = hA[0]*wr[0];   a1  = hA[1]*wr[1];
    a0 += hA[2]*wr[2];   a1 += hA[3]*wr[3];
    a0 += hB[0]*wr[4];   a1 += hB[1]*wr[5];
    a0 += hB[2]*wr[6];   a1 += hB[3]*wr[7];
    a0 += hC[0]*wr[8];   a1 += hC[1]*wr[9];
    a0 += hC[2]*wr[10];  a1 += hC[3]*wr[11];
    a0 += hD[0]*wr[12];  a1 += hD[1]*wr[13];
    a0 += hD[2]*wr[14];  a1 += hD[3]*wr[15];
    f32x4 acc = a0 + a1;

    // ---- quad all-reduce over kc via DPP rotations (VALU only) ----
    #pragma unroll
    for (int c=0;c<4;c++){
      float v = acc[c];
      v += dpp_rot<0x39>(v);   // + lane(q+1 mod 4): perm {1,2,3,0}
      v += dpp_rot<0x4E>(v);   // + rotated by 2:    perm {2,3,0,1}
      acc[c] = v;
    }
    if (kc == 0) *(f32x4*)redw = acc;   // one writer per quad

    asm volatile("s_waitcnt lgkmcnt(0)" ::: "memory");
    __builtin_amdgcn_s_barrier();
    asm volatile("" ::: "memory");

    // ---- phase B: finish (waves 0-3; thread handles output j = tid) ----
    if (tid < 256){
      float p2 = 0.f;
      if (t + 2 < SEQ) p2 = prep[0];
      prep += (size_t)NB*256;
      float s = pv + red[tid] + red[256+tid] + red[512+tid] + red[768+tid];
      float e = __expf(2.f*s);          // tanh(s) = 1 - 2/(e^(2s)+1)
      float h = 1.f - 2.f*__builtin_amdgcn_rcpf(e + 1.f);
      hbuf[tid] = h;
      *Hp = f2bf(h);                    // store stays in flight (no vmcnt drain)
      Hp += (size_t)NB*256;
      pv = p1; p1 = p2;
    }

    asm volatile("s_waitcnt lgkmcnt(0)" ::: "memory");
    __builtin_amdgcn_s_barrier();
    asm volatile("" ::: "memory");
  }
}

extern "C" void kernel_launch(void* const* d_in, const int* in_sizes, int n_in,
                              void* d_out, int out_size, void* d_ws, size_t ws_size,
                              hipStream_t stream) {
  const float* x     = (const float*)d_in[0];
  const float* h0    = (const float*)d_in[1];
  const float* i2h   = (const float*)d_in[2];
  const float* i2h_b = (const float*)d_in[3];
  const float* h2o   = (const float*)d_in[4];
  const float* h2o_b = (const float*)d_in[5];
  float* out = (float*)d_out;

  // ws layout: [0,64MB) x_bf16, later aliased by H_bf16 (x_bf16 dead after gemm1)
  //            [64MB, +256KB) BT1, BT3
  unsigned short* xb  = (unsigned short*)d_ws;
  unsigned short* BT1 = (unsigned short*)((char*)d_ws + (size_t)M_TOTAL*HID*2);
  unsigned short* BT3 = BT1 + 256*256;

  k_convert_x<<<M_TOTAL*HID/(256*4), 256, 0, stream>>>(x, xb);
  k_convert_w<<<256, 256, 0, stream>>>(i2h, h2o, BT1, BT3);

  dim3 g1(M_TOTAL/128, 2);
  // pre = x @ W_xh + i2h_bias  -> stored in d_out (fp32), consumed by scan
  k_gemm<<<g1, 256, 0, stream>>>(xb, BT1, i2h_b, out);
  // sequential recurrence; writes H (bf16) over the xb region
  k_scan<<<NB, 1024, 0, stream>>>(i2h, h0, out, xb);
  // y = H @ W_ho + h2o_bias -> d_out (overwrites pre)
  k_gemm<<<g1, 256, 0, stream>>>(xb, BT3, h2o_b, out);
}